// Round 8
// baseline (194.649 us; speedup 1.0000x reference)
//
#include <hip/hip_runtime.h>

#define HW  (512 * 512)   // 262144 = 2^18
#define NC  16
#define NB  4
#define GW  512
#define GH  512
#define TILE 16
#define HALO 18           // TILE + 2
#define NSU  12           // uints per node in LDS: 8 data (16 f16) + 4 pad -> 48B, 16B-aligned

// ---- packed f16 helpers (payload is 2 x _Float16 per uint; lo = even ch, hi = odd ch)
typedef _Float16 h2 __attribute__((ext_vector_type(2)));
typedef __fp16  h2raw __attribute__((ext_vector_type(2)));   // builtin return type

__device__ __forceinline__ unsigned int pk16(float a, float b) {
    h2raw h = __builtin_amdgcn_cvt_pkrtz(a, b);    // v_cvt_pkrtz_f16_f32: 1 instr
    return __builtin_bit_cast(unsigned int, h);
}
__device__ __forceinline__ h2 asH(unsigned int u) {
    return __builtin_bit_cast(h2, u);
}
__device__ __forceinline__ float flo(unsigned int u) { return (float)asH(u).x; }
__device__ __forceinline__ float fhi(unsigned int u) { return (float)asH(u).y; }
// |x - y| elementwise on a packed pair: v_pk_add_f16(neg) + v_and_b32
__device__ __forceinline__ h2 absdiff(h2 x, h2 y) {
    h2 d = x - y;
    unsigned int u = __builtin_bit_cast(unsigned int, d) & 0x7fff7fffu;
    return __builtin_bit_cast(h2, u);
}

// edges strictly before node (h,w) in node-major, offset-ordered enumeration
__device__ __forceinline__ int edge_prefix(int h, int w) {
    if (h == 0) return (w == 0) ? 0 : 3 + 5 * (w - 1);
    int p = 2556 + 4090 * (h - 1);
    if (h == GH - 1) return p + ((w == 0) ? 0 : 3 + 5 * (w - 1));
    return p + ((w == 0) ? 0 : 5 + 8 * (w - 1));
}
__device__ __forceinline__ int degree(int h, int w) {
    int rh = 1 + (h > 0) + (h < GH - 1);
    int rw = 1 + (w > 0) + (w < GW - 1);
    return rh * rw - 1;
}

// ============================================================================
// k_stage: one block per (tile, batch). 4096 blocks -> 16 blocks/CU queued,
// ~8 co-resident (15.5 KB LDS, ~56 VGPR) = up to 32 waves/CU of UNCORRELATED
// phases. Stages its batch's 18x18 halo to LDS (f16-packed), writes nf_out
// for its batch, computes per-node 8-neighbor partial sums -> ws (f32).
// ============================================================================
__global__ __launch_bounds__(256) void k_stage(const float* __restrict__ g,
                                               float* __restrict__ nf_out,
                                               float* __restrict__ ws) {
    __shared__ unsigned int nds[HALO * HALO * NSU];   // 15552 B

    const int tid = threadIdx.x;
    // XCD swizzle (R2 win): XCD k owns a 16x8-tile rectangle; within an XCD,
    // a tile's 4 batch-blocks are adjacent in issue order (b = fast bits) so
    // the tile halo is read from L2 across batches' channel planes.
    const int xk   = blockIdx.x & 7;
    const int rest = blockIdx.x >> 3;
    const int b    = rest & 3;
    const int m    = rest >> 2;                   // 0..127
    const int by = ((xk >> 2) << 4) | (m >> 3);   // tile row 0..31
    const int bx = ((xk & 3) << 3) | (m & 7);     // tile col 0..31
    const int til = by * 32 + bx;                 // tile id (row-major)
    const int h0 = by * TILE, w0 = bx * TILE;
    const int tr = tid >> 4, tc = tid & 15;

    const int OFF_H[8] = {-1, -1, -1, 0, 0, 1, 1, 1};
    const int OFF_W[8] = {-1, 0, 1, -1, 1, -1, 0, 1};

    // ---- phase 1: stage batch b. 8 c2 x 18 rows x 6 float4 = 864 slots.
    for (int r = 0; r < 4; ++r) {
        int idx = r * 256 + tid;
        if (idx < 864) {
            int f4  = idx % 6;
            int t   = idx / 6;
            int row = t % 18;
            int c2  = t / 18;                         // 0..7 (channel pair)
            int hh  = min(max(h0 - 1 + row, 0), GH - 1);
            int gw  = min(max(w0 - 4 + 4 * f4, 0), GW - 4);
            const float* pA = g + (((size_t)(b * 16 + 2 * c2)) << 18) + (hh << 9) + gw;
            const float4 A = *(const float4*)pA;
            const float4 B = *(const float4*)(pA + HW);
#pragma unroll
            for (int j = 0; j < 4; ++j) {
                int hc = 4 * f4 + j - 3;              // halo col: window pos - 3
                if ((unsigned)hc < (unsigned)HALO) {
                    float a  = ((const float*)&A)[j];
                    float bb = ((const float*)&B)[j];
                    nds[(row * HALO + hc) * NSU + c2] = pk16(a, bb);
                }
            }
        }
    }
    __syncthreads();

    // ---- phase 2: nf_out for batch b. 1024 float4 slots.
#pragma unroll
    for (int s = 0; s < 4; ++s) {
        int o4 = s * 256 + tid;
        int c4 = o4 & 3;
        int nl256 = o4 >> 2;
        int pr = nl256 >> 4, pc = nl256 & 15;
        int nl = (pr + 1) * HALO + (pc + 1);
        unsigned int u0 = nds[nl * NSU + 2 * c4];
        unsigned int u1 = nds[nl * NSU + 2 * c4 + 1];
        int n = (h0 + pr) * GW + (w0 + pc);
        float4* dst = (float4*)(nf_out + (((size_t)b << 18) + n) * NC + 4 * c4);
        *dst = make_float4(flo(u0), fhi(u0), flo(u1), fhi(u1));
    }

    // ---- phase 3: 8 neighbor diffs (R5 interleaved form)
    float acc[8];
    {
        const uint4* p = (const uint4*)nds;
        int nl_self = (tr + 1) * HALO + (tc + 1);
        uint4 s0 = p[nl_self * 3];
        uint4 s1 = p[nl_self * 3 + 1];
        h2 sf[8] = { asH(s0.x), asH(s0.y), asH(s0.z), asH(s0.w),
                     asH(s1.x), asH(s1.y), asH(s1.z), asH(s1.w) };
#pragma unroll
        for (int k = 0; k < 8; ++k) {
            int nl_n = (tr + 1 + OFF_H[k]) * HALO + (tc + 1 + OFF_W[k]);
            uint4 n0 = p[nl_n * 3];
            uint4 n1 = p[nl_n * 3 + 1];
            h2 a0 = absdiff(sf[0], asH(n0.x));
            h2 a1 = absdiff(sf[1], asH(n0.y));
            h2 a2 = absdiff(sf[2], asH(n0.z));
            h2 a3 = absdiff(sf[3], asH(n0.w));
            h2 a4 = absdiff(sf[4], asH(n1.x));
            h2 a5 = absdiff(sf[5], asH(n1.y));
            h2 a6 = absdiff(sf[6], asH(n1.z));
            h2 a7 = absdiff(sf[7], asH(n1.w));
            h2 b0 = a0 + a1, b1 = a2 + a3, b2 = a4 + a5, b3 = a6 + a7;
            h2 c0 = b0 + b1, c1 = b2 + b3;
            acc[k] = ((float)c0.x + (float)c0.y) + ((float)c1.x + (float)c1.y);
        }
    }

    // ---- write per-node partials (pre-scaled): ws[(til*4+b)*2048 + tid*8 + k]
    // thread -> 32B contiguous, block -> 8 KB fully coalesced.
    {
        float4* wp = (float4*)ws + ((size_t)(til * 4 + b) << 9) + tid * 2;
        wp[0] = make_float4(acc[0] * (1.0f / 64.0f), acc[1] * (1.0f / 64.0f),
                            acc[2] * (1.0f / 64.0f), acc[3] * (1.0f / 64.0f));
        wp[1] = make_float4(acc[4] * (1.0f / 64.0f), acc[5] * (1.0f / 64.0f),
                            acc[6] * (1.0f / 64.0f), acc[7] * (1.0f / 64.0f));
    }
}

// ============================================================================
// k_edge: one block per tile. Sums the 4 batch partials from ws (same XCD
// swizzle as k_stage -> producer-L2 hits), valid-packs to LDS, writes edge
// outputs (identical to the proven phase 4).
// ============================================================================
__global__ __launch_bounds__(256) void k_edge(const float* __restrict__ ws,
                                              float* __restrict__ ei_out,
                                              float* __restrict__ attr_out,
                                              int E) {
    __shared__ float fdbuf[256 * 9];   // 9216 B

    const int tid = threadIdx.x;
    const int xk = blockIdx.x & 7;
    const int m  = blockIdx.x >> 3;
    const int by = ((xk >> 2) << 4) | (m >> 3);
    const int bx = ((xk & 3) << 3) | (m & 7);
    const int til = by * 32 + bx;
    const int h0 = by * TILE, w0 = bx * TILE;
    const int tr = tid >> 4, tc = tid & 15;

    const int OFF_H[8] = {-1, -1, -1, 0, 0, 1, 1, 1};
    const int OFF_W[8] = {-1, 0, 1, -1, 1, -1, 0, 1};

    // ---- sum 4 batch partials (per-thread 2 float4 per batch, coalesced)
    const float4* base = (const float4*)ws + ((size_t)til << 11) + tid * 2;
    float4 a0 = base[0],    a1 = base[1];
    float4 b0 = base[512],  b1 = base[513];
    float4 c0 = base[1024], c1 = base[1025];
    float4 d0 = base[1536], d1 = base[1537];
    float f[8] = { a0.x + b0.x + c0.x + d0.x,  a0.y + b0.y + c0.y + d0.y,
                   a0.z + b0.z + c0.z + d0.z,  a0.w + b0.w + c0.w + d0.w,
                   a1.x + b1.x + c1.x + d1.x,  a1.y + b1.y + c1.y + d1.y,
                   a1.z + b1.z + c1.z + d1.z,  a1.w + b1.w + c1.w + d1.w };

    // ---- valid-pack per-node fdiffs (pad-9 stride)
    {
        int h = h0 + tr, w = w0 + tc;
        int cnt = 0;
#pragma unroll
        for (int k = 0; k < 8; ++k) {
            if ((unsigned)(h + OFF_H[k]) < (unsigned)GH &&
                (unsigned)(w + OFF_W[k]) < (unsigned)GW) {
                fdbuf[tid * 9 + cnt] = f[k];
                ++cnt;
            }
        }
    }
    __syncthreads();

    // ---- phase 4: edge outputs, edge-major (lane-consecutive stores)
#pragma unroll
    for (int r = 0; r < 8; ++r) {
        int u2    = r * 256 + tid;
        int chunk = u2 >> 7;             // tile row 0..15
        int e     = u2 & 127;
        int h     = h0 + chunk;
        int first = degree(h, w0);
        int mid   = degree(h, w0 + 1);
        int last  = degree(h, w0 + TILE - 1);
        int Lr    = first + 14 * mid + last;
        if (e < Lr) {
            int node_in_row, k;
            if (e < first) { node_in_row = 0; k = e; }
            else {
                int m2 = e - first;
                if (mid == 8) { node_in_row = 1 + (m2 >> 3); k = m2 & 7; }
                else          { int q = m2 / 5; node_in_row = 1 + q; k = m2 - 5 * q; }
            }
            int w = w0 + node_in_row;
            int n = h * GW + w;
            int idx = 0, cnt2 = 0;
#pragma unroll
            for (int i = 0; i < 8; ++i) {
                bool ok = (unsigned)(h + OFF_H[i]) < (unsigned)GH &&
                          (unsigned)(w + OFF_W[i]) < (unsigned)GW;
                if (ok) { if (cnt2 == k) idx = i; ++cnt2; }
            }
            int dh = OFF_H[idx], dw = OFF_W[idx];
            float dist = (dh != 0 && dw != 0) ? 1.41421356237f : 1.0f;
            float fd = fdbuf[(chunk * 16 + node_in_row) * 9 + k];
            int o = edge_prefix(h, w0) + e;
            ei_out[o]     = (float)n;
            ei_out[E + o] = (float)(n + dh * GW + dw);
            *(float2*)(attr_out + 2 * (size_t)o) = make_float2(dist, fd);
        }
    }
}

extern "C" void kernel_launch(void* const* d_in, const int* in_sizes, int n_in,
                              void* d_out, int out_size, void* d_ws, size_t ws_size,
                              hipStream_t stream) {
    const float* g = (const float*)d_in[0];    // f32 grid (B,C,H,W)
    int E = in_sizes[1] / 2;                   // 2091012 (ei input not read)

    float* out      = (float*)d_out;
    float* nf_out   = out;                                   // (B*HW, C)  f32
    float* ei_out   = out + (size_t)NB * HW * NC;            // (2, E)     f32
    float* attr_out = ei_out + (size_t)2 * E;                // (E, 2)     f32
    float* ws       = (float*)d_ws;                          // 4096 x 2048 f32 = 32 MB

    k_stage<<<1024 * NB, 256, 0, stream>>>(g, nf_out, ws);
    k_edge<<<1024, 256, 0, stream>>>(ws, ei_out, attr_out, E);
}

// Round 10
// 174.234 us; speedup vs baseline: 1.1172x; 1.1172x over previous
//
#include <hip/hip_runtime.h>

#define HW  (512 * 512)   // 262144 = 2^18
#define NC  16
#define NB  4
#define GW  512
#define GH  512
#define TILE 16
#define HALO 18           // TILE + 2
#define NSU  12           // uints per node in LDS: 8 data (16 f16) + 4 pad -> 48B, 16B-aligned
#define NDS_U (HALO * HALO * NSU)

// ---- packed f16 helpers (payload is 2 x _Float16 per uint; lo = even ch, hi = odd ch)
typedef _Float16 h2 __attribute__((ext_vector_type(2)));
typedef __fp16  h2raw __attribute__((ext_vector_type(2)));   // builtin return type
// native clang vectors for __builtin_nontemporal_store (HIP_vector_type is a
// class -> rejected by the builtin; these are layout-identical)
typedef float f4v __attribute__((ext_vector_type(4)));
typedef float f2v __attribute__((ext_vector_type(2)));

__device__ __forceinline__ unsigned int pk16(float a, float b) {
    h2raw h = __builtin_amdgcn_cvt_pkrtz(a, b);    // v_cvt_pkrtz_f16_f32: 1 instr
    return __builtin_bit_cast(unsigned int, h);
}
__device__ __forceinline__ h2 asH(unsigned int u) {
    return __builtin_bit_cast(h2, u);
}
__device__ __forceinline__ float flo(unsigned int u) { return (float)asH(u).x; }
__device__ __forceinline__ float fhi(unsigned int u) { return (float)asH(u).y; }
// |x - y| elementwise on a packed pair: v_pk_add_f16(neg) + v_and_b32
__device__ __forceinline__ h2 absdiff(h2 x, h2 y) {
    h2 d = x - y;
    unsigned int u = __builtin_bit_cast(unsigned int, d) & 0x7fff7fffu;
    return __builtin_bit_cast(h2, u);
}

// edges strictly before node (h,w) in node-major, offset-ordered enumeration
__device__ __forceinline__ int edge_prefix(int h, int w) {
    if (h == 0) return (w == 0) ? 0 : 3 + 5 * (w - 1);
    int p = 2556 + 4090 * (h - 1);
    if (h == GH - 1) return p + ((w == 0) ? 0 : 3 + 5 * (w - 1));
    return p + ((w == 0) ? 0 : 5 + 8 * (w - 1));
}
__device__ __forceinline__ int degree(int h, int w) {
    int rh = 1 + (h > 0) + (h < GH - 1);
    int rw = 1 + (w > 0) + (w < GW - 1);
    return rh * rw - 1;
}

// ---- T14 async-STAGE split, double-buffered: loads issued right AFTER the
// iteration barrier (so __syncthreads' vmcnt(0) drain never waits on them),
// consumed ~2-3k cycles later by the next STAGE_WRITE into the other buffer.
#define STAGE_LOAD(bb)                                                         \
    do {                                                                       \
        _Pragma("unroll") for (int r = 0; r < 4; ++r) if (vld[r]) {            \
            const float* p = g + (size_t)off0[r] + ((size_t)(bb) << 22);       \
            LA[r] = *(const float4*)p;                                         \
            LB[r] = *(const float4*)(p + HW);                                  \
        }                                                                      \
    } while (0)

#define STAGE_WRITE(buf)                                                       \
    do {                                                                       \
        _Pragma("unroll") for (int r = 0; r < 4; ++r) if (vld[r]) {            \
            _Pragma("unroll") for (int j = 0; j < 4; ++j) {                    \
                int hc = vhc[r] + j;                                           \
                if ((unsigned)hc < (unsigned)HALO)                             \
                    (buf)[vslot[r] + j * NSU] =                                \
                        pk16(((const float*)&LA[r])[j], ((const float*)&LB[r])[j]); \
            }                                                                  \
        }                                                                      \
    } while (0)

__global__ __launch_bounds__(256) void k_fused(const float* __restrict__ g,
                                               float* __restrict__ nf_out,
                                               float* __restrict__ ei_out,
                                               float* __restrict__ attr_out,
                                               int E) {
    __shared__ unsigned int nds[2][NDS_U];   // 2 x 15552 B, f16-packed node-major
    float* fdbuf = (float*)nds;               // overlay after batch loop (9216 B)

    const int tid = threadIdx.x;
    // 2D-chunk XCD swizzle (round-2 win: FETCH 127->47 MB): XCD k gets a 16x8-tile
    // rectangle; per-batch read working set ~2.1 MB < 4 MB L2. Bijective.
    const int xk = blockIdx.x & 7;
    const int m  = blockIdx.x >> 3;
    const int by = ((xk >> 2) << 4) | (m >> 3);   // tile row 0..31
    const int bx = ((xk & 3) << 3) | (m & 7);     // tile col 0..31
    const int h0 = by * TILE, w0 = bx * TILE;
    const int tr = tid >> 4, tc = tid & 15;

    const int OFF_H[8] = {-1, -1, -1, 0, 0, 1, 1, 1};
    const int OFF_W[8] = {-1, 0, 1, -1, 1, -1, 0, 1};

    // ---- staging slot metadata (batch-invariant, held in ~16 VGPRs).
    // Slot space: 8 c2 x 18 rows x 6 float4-windows = 864 slots over 256 thr.
    bool vld[4];
    int off0[4], vslot[4], vhc[4];
#pragma unroll
    for (int r = 0; r < 4; ++r) {
        int idx = r * 256 + tid;
        vld[r] = idx < 864;
        int i2  = vld[r] ? idx : 0;
        int f4  = i2 % 6;
        int t   = i2 / 6;
        int row = t % 18;
        int c2  = t / 18;                                 // 0..7 (channel pair)
        int hh  = min(max(h0 - 1 + row, 0), GH - 1);
        int gw  = min(max(w0 - 4 + 4 * f4, 0), GW - 4);
        off0[r]  = ((2 * c2) << 18) + (hh << 9) + gw;     // batch-0 element offset
        vhc[r]   = 4 * f4 - 3;
        vslot[r] = (row * HALO + vhc[r]) * NSU + c2;
    }

    float acc[8];
#pragma unroll
    for (int k = 0; k < 8; ++k) acc[k] = 0.0f;

    float4 LA[4], LB[4];
    STAGE_LOAD(0);   // prologue prefetch (exposed once)

#pragma unroll 1     // keep rolled: avoids R1's live-range explosion -> spill
    for (int b = 0; b < NB; ++b) {
        unsigned int* buf = nds[b & 1];

        // ---- phase 1b: pack prefetched regs -> LDS (vmcnt wait lands here;
        // loads have had all of prev iteration's phase2+3 to complete)
        STAGE_WRITE(buf);
        __syncthreads();

        // ---- issue next batch's global loads NOW (after the barrier drain,
        // so the drain never waits on them). They fly under phase2+phase3.
        if (b + 1 < NB) STAGE_LOAD(b + 1);

        // ---- phase 2: nf_out for batch b. 1024 float4 slots; each wave's 64
        // lanes store 1 KB contiguous. NT store: nf is never re-read -> bypass
        // L2/LLC allocation so the 64 MB input stays LLC-resident (R9 theory).
#pragma unroll
        for (int s = 0; s < 4; ++s) {
            int o4 = s * 256 + tid;
            int c4 = o4 & 3;
            int nl256 = o4 >> 2;
            int pr = nl256 >> 4, pc = nl256 & 15;
            int nl = (pr + 1) * HALO + (pc + 1);
            unsigned int u0 = buf[nl * NSU + 2 * c4];
            unsigned int u1 = buf[nl * NSU + 2 * c4 + 1];
            int n = (h0 + pr) * GW + (w0 + pc);
            f4v* dst = (f4v*)(nf_out + (((size_t)b << 18) + n) * NC + 4 * c4);
            f4v v; v.x = flo(u0); v.y = fhi(u0); v.z = flo(u1); v.w = fhi(u1);
            __builtin_nontemporal_store(v, dst);
        }

        // ---- phase 3: accumulate 8 neighbor diffs (R5 interleaved form —
        // read k, compute k; compiler pipelines adjacent iterations).
        {
            const uint4* p = (const uint4*)buf;
            int nl_self = (tr + 1) * HALO + (tc + 1);
            uint4 s0 = p[nl_self * 3];
            uint4 s1 = p[nl_self * 3 + 1];
            h2 sf[8] = { asH(s0.x), asH(s0.y), asH(s0.z), asH(s0.w),
                         asH(s1.x), asH(s1.y), asH(s1.z), asH(s1.w) };
#pragma unroll
            for (int k = 0; k < 8; ++k) {
                int nl_n = (tr + 1 + OFF_H[k]) * HALO + (tc + 1 + OFF_W[k]);
                uint4 n0 = p[nl_n * 3];
                uint4 n1 = p[nl_n * 3 + 1];
                h2 a0 = absdiff(sf[0], asH(n0.x));
                h2 a1 = absdiff(sf[1], asH(n0.y));
                h2 a2 = absdiff(sf[2], asH(n0.z));
                h2 a3 = absdiff(sf[3], asH(n0.w));
                h2 a4 = absdiff(sf[4], asH(n1.x));
                h2 a5 = absdiff(sf[5], asH(n1.y));
                h2 a6 = absdiff(sf[6], asH(n1.z));
                h2 a7 = absdiff(sf[7], asH(n1.w));
                // 2-level packed tree (stop at 4-wide partials to bound f16 rounding)
                h2 b0 = a0 + a1, b1 = a2 + a3, b2 = a4 + a5, b3 = a6 + a7;
                h2 c0 = b0 + b1, c1 = b2 + b3;
                acc[k] += ((float)c0.x + (float)c0.y) + ((float)c1.x + (float)c1.y);
            }
        }
    }

    __syncthreads();   // all phase-3 reads of nds complete -> overlay fdbuf

    // ---- write per-node fdiffs (valid-packed, pad-9 stride)
    {
        int h = h0 + tr, w = w0 + tc;
        int cnt = 0;
#pragma unroll
        for (int k = 0; k < 8; ++k) {
            if ((unsigned)(h + OFF_H[k]) < (unsigned)GH &&
                (unsigned)(w + OFF_W[k]) < (unsigned)GW) {
                fdbuf[tid * 9 + cnt] = acc[k] * (1.0f / 64.0f);
                ++cnt;
            }
        }
    }
    __syncthreads();

    // ---- phase 4: edge outputs, edge-major (lane-consecutive NT stores)
#pragma unroll
    for (int r = 0; r < 8; ++r) {
        int u2    = r * 256 + tid;
        int chunk = u2 >> 7;             // tile row 0..15
        int e     = u2 & 127;
        int h     = h0 + chunk;
        int first = degree(h, w0);
        int mid   = degree(h, w0 + 1);
        int last  = degree(h, w0 + TILE - 1);
        int Lr    = first + 14 * mid + last;
        if (e < Lr) {
            int node_in_row, k;
            if (e < first) { node_in_row = 0; k = e; }
            else {
                int m2 = e - first;
                if (mid == 8) { node_in_row = 1 + (m2 >> 3); k = m2 & 7; }
                else          { int q = m2 / 5; node_in_row = 1 + q; k = m2 - 5 * q; }
            }
            int w = w0 + node_in_row;
            int n = h * GW + w;
            int idx = 0, cnt2 = 0;
#pragma unroll
            for (int i = 0; i < 8; ++i) {
                bool ok = (unsigned)(h + OFF_H[i]) < (unsigned)GH &&
                          (unsigned)(w + OFF_W[i]) < (unsigned)GW;
                if (ok) { if (cnt2 == k) idx = i; ++cnt2; }
            }
            int dh = OFF_H[idx], dw = OFF_W[idx];
            float dist = (dh != 0 && dw != 0) ? 1.41421356237f : 1.0f;
            float fd = fdbuf[(chunk * 16 + node_in_row) * 9 + k];
            int o = edge_prefix(h, w0) + e;
            __builtin_nontemporal_store((float)n, ei_out + o);
            __builtin_nontemporal_store((float)(n + dh * GW + dw), ei_out + E + o);
            f2v av; av.x = dist; av.y = fd;
            __builtin_nontemporal_store(av, (f2v*)(attr_out + 2 * (size_t)o));
        }
    }
}

extern "C" void kernel_launch(void* const* d_in, const int* in_sizes, int n_in,
                              void* d_out, int out_size, void* d_ws, size_t ws_size,
                              hipStream_t stream) {
    const float* g = (const float*)d_in[0];    // f32 grid (B,C,H,W)
    int E = in_sizes[1] / 2;                   // 2091012 (ei input not read)

    float* out      = (float*)d_out;
    float* nf_out   = out;                                   // (B*HW, C)  f32
    float* ei_out   = out + (size_t)NB * HW * NC;            // (2, E)     f32
    float* attr_out = ei_out + (size_t)2 * E;                // (E, 2)     f32

    k_fused<<<(GH / TILE) * (GW / TILE), 256, 0, stream>>>(g, nf_out, ei_out, attr_out, E);
}

// Round 11
// 173.692 us; speedup vs baseline: 1.1207x; 1.0031x over previous
//
#include <hip/hip_runtime.h>

#define HW  (512 * 512)   // 262144 = 2^18
#define NC  16
#define NB  4
#define GW  512
#define GH  512
#define TILE 16
#define HALO 18           // TILE + 2
#define NSU  12           // uints per node in LDS: 8 data (16 f16) + 4 pad -> 48B, 16B-aligned
#define NDS_U (HALO * HALO * NSU)

// ---- packed f16 helpers (payload is 2 x _Float16 per uint; lo = even ch, hi = odd ch)
typedef _Float16 h2 __attribute__((ext_vector_type(2)));
typedef __fp16  h2raw __attribute__((ext_vector_type(2)));   // builtin return type
// native clang vectors for nontemporal builtin / asm payloads
typedef float f4v __attribute__((ext_vector_type(4)));
typedef float f2v __attribute__((ext_vector_type(2)));

__device__ __forceinline__ unsigned int pk16(float a, float b) {
    h2raw h = __builtin_amdgcn_cvt_pkrtz(a, b);    // v_cvt_pkrtz_f16_f32: 1 instr
    return __builtin_bit_cast(unsigned int, h);
}
__device__ __forceinline__ h2 asH(unsigned int u) {
    return __builtin_bit_cast(h2, u);
}
__device__ __forceinline__ float flo(unsigned int u) { return (float)asH(u).x; }
__device__ __forceinline__ float fhi(unsigned int u) { return (float)asH(u).y; }
// |x - y| elementwise on a packed pair: v_pk_add_f16(neg) + v_and_b32
__device__ __forceinline__ h2 absdiff(h2 x, h2 y) {
    h2 d = x - y;
    unsigned int u = __builtin_bit_cast(unsigned int, d) & 0x7fff7fffu;
    return __builtin_bit_cast(h2, u);
}

// streaming store: no-allocate at L1+L2 (sc0 sc1 nt) — the fillBuffer-class
// write path (6.5 TB/s measured R10) instead of L2 write-allocate+evict.
__device__ __forceinline__ void stream_store4(f4v v, f4v* dst) {
    asm volatile("global_store_dwordx4 %0, %1, off sc0 sc1 nt"
                 :: "v"(dst), "v"(v));
}

// edges strictly before node (h,w) in node-major, offset-ordered enumeration
__device__ __forceinline__ int edge_prefix(int h, int w) {
    if (h == 0) return (w == 0) ? 0 : 3 + 5 * (w - 1);
    int p = 2556 + 4090 * (h - 1);
    if (h == GH - 1) return p + ((w == 0) ? 0 : 3 + 5 * (w - 1));
    return p + ((w == 0) ? 0 : 5 + 8 * (w - 1));
}
__device__ __forceinline__ int degree(int h, int w) {
    int rh = 1 + (h > 0) + (h < GH - 1);
    int rw = 1 + (w > 0) + (w < GW - 1);
    return rh * rw - 1;
}

// ---- T14 async-STAGE split, double-buffered: loads issued right AFTER the
// iteration barrier (so __syncthreads' vmcnt(0) drain never waits on them),
// consumed ~2-3k cycles later by the next STAGE_WRITE into the other buffer.
#define STAGE_LOAD(bb)                                                         \
    do {                                                                       \
        _Pragma("unroll") for (int r = 0; r < 4; ++r) if (vld[r]) {            \
            const float* p = g + (size_t)off0[r] + ((size_t)(bb) << 22);       \
            LA[r] = *(const float4*)p;                                         \
            LB[r] = *(const float4*)(p + HW);                                  \
        }                                                                      \
    } while (0)

#define STAGE_WRITE(buf)                                                       \
    do {                                                                       \
        _Pragma("unroll") for (int r = 0; r < 4; ++r) if (vld[r]) {            \
            _Pragma("unroll") for (int j = 0; j < 4; ++j) {                    \
                int hc = vhc[r] + j;                                           \
                if ((unsigned)hc < (unsigned)HALO)                             \
                    (buf)[vslot[r] + j * NSU] =                                \
                        pk16(((const float*)&LA[r])[j], ((const float*)&LB[r])[j]); \
            }                                                                  \
        }                                                                      \
    } while (0)

__global__ __launch_bounds__(256) void k_fused(const float* __restrict__ g,
                                               float* __restrict__ nf_out,
                                               float* __restrict__ ei_out,
                                               float* __restrict__ attr_out,
                                               int E) {
    __shared__ unsigned int nds[2][NDS_U];   // 2 x 15552 B, f16-packed node-major
    float* fdbuf = (float*)nds;               // overlay after batch loop (9216 B)

    const int tid = threadIdx.x;
    // 2D-chunk XCD swizzle (round-2 win: FETCH 127->47 MB): XCD k gets a 16x8-tile
    // rectangle; per-batch read working set ~2.1 MB < 4 MB L2. Bijective.
    const int xk = blockIdx.x & 7;
    const int m  = blockIdx.x >> 3;
    const int by = ((xk >> 2) << 4) | (m >> 3);   // tile row 0..31
    const int bx = ((xk & 3) << 3) | (m & 7);     // tile col 0..31
    const int h0 = by * TILE, w0 = bx * TILE;
    const int tr = tid >> 4, tc = tid & 15;

    const int OFF_H[8] = {-1, -1, -1, 0, 0, 1, 1, 1};
    const int OFF_W[8] = {-1, 0, 1, -1, 1, -1, 0, 1};

    // ---- staging slot metadata (batch-invariant, held in ~16 VGPRs).
    // Slot space: 8 c2 x 18 rows x 6 float4-windows = 864 slots over 256 thr.
    bool vld[4];
    int off0[4], vslot[4], vhc[4];
#pragma unroll
    for (int r = 0; r < 4; ++r) {
        int idx = r * 256 + tid;
        vld[r] = idx < 864;
        int i2  = vld[r] ? idx : 0;
        int f4  = i2 % 6;
        int t   = i2 / 6;
        int row = t % 18;
        int c2  = t / 18;                                 // 0..7 (channel pair)
        int hh  = min(max(h0 - 1 + row, 0), GH - 1);
        int gw  = min(max(w0 - 4 + 4 * f4, 0), GW - 4);
        off0[r]  = ((2 * c2) << 18) + (hh << 9) + gw;     // batch-0 element offset
        vhc[r]   = 4 * f4 - 3;
        vslot[r] = (row * HALO + vhc[r]) * NSU + c2;
    }

    float acc[8];
#pragma unroll
    for (int k = 0; k < 8; ++k) acc[k] = 0.0f;

    float4 LA[4], LB[4];
    STAGE_LOAD(0);   // prologue prefetch (exposed once)

#pragma unroll 1     // keep rolled: avoids R1's live-range explosion -> spill
    for (int b = 0; b < NB; ++b) {
        unsigned int* buf = nds[b & 1];

        // ---- phase 1b: pack prefetched regs -> LDS (vmcnt wait lands here;
        // loads have had all of prev iteration's phase2+3 to complete)
        STAGE_WRITE(buf);
        __syncthreads();

        // ---- issue next batch's global loads NOW (after the barrier drain,
        // so the drain never waits on them). They fly under phase2+phase3.
        if (b + 1 < NB) STAGE_LOAD(b + 1);

        // ---- phase 2: nf_out for batch b. 1024 float4 slots; each wave's 64
        // lanes store 1 KB contiguous. STREAMING store (sc0 sc1 nt): no
        // L2 write-allocate -> no eviction storm against staging reads.
#pragma unroll
        for (int s = 0; s < 4; ++s) {
            int o4 = s * 256 + tid;
            int c4 = o4 & 3;
            int nl256 = o4 >> 2;
            int pr = nl256 >> 4, pc = nl256 & 15;
            int nl = (pr + 1) * HALO + (pc + 1);
            unsigned int u0 = buf[nl * NSU + 2 * c4];
            unsigned int u1 = buf[nl * NSU + 2 * c4 + 1];
            int n = (h0 + pr) * GW + (w0 + pc);
            f4v* dst = (f4v*)(nf_out + (((size_t)b << 18) + n) * NC + 4 * c4);
            f4v v; v.x = flo(u0); v.y = fhi(u0); v.z = flo(u1); v.w = fhi(u1);
            stream_store4(v, dst);
        }

        // ---- phase 3: accumulate 8 neighbor diffs (R5 interleaved form —
        // read k, compute k; compiler pipelines adjacent iterations).
        {
            const uint4* p = (const uint4*)buf;
            int nl_self = (tr + 1) * HALO + (tc + 1);
            uint4 s0 = p[nl_self * 3];
            uint4 s1 = p[nl_self * 3 + 1];
            h2 sf[8] = { asH(s0.x), asH(s0.y), asH(s0.z), asH(s0.w),
                         asH(s1.x), asH(s1.y), asH(s1.z), asH(s1.w) };
#pragma unroll
            for (int k = 0; k < 8; ++k) {
                int nl_n = (tr + 1 + OFF_H[k]) * HALO + (tc + 1 + OFF_W[k]);
                uint4 n0 = p[nl_n * 3];
                uint4 n1 = p[nl_n * 3 + 1];
                h2 a0 = absdiff(sf[0], asH(n0.x));
                h2 a1 = absdiff(sf[1], asH(n0.y));
                h2 a2 = absdiff(sf[2], asH(n0.z));
                h2 a3 = absdiff(sf[3], asH(n0.w));
                h2 a4 = absdiff(sf[4], asH(n1.x));
                h2 a5 = absdiff(sf[5], asH(n1.y));
                h2 a6 = absdiff(sf[6], asH(n1.z));
                h2 a7 = absdiff(sf[7], asH(n1.w));
                // 2-level packed tree (stop at 4-wide partials to bound f16 rounding)
                h2 b0 = a0 + a1, b1 = a2 + a3, b2 = a4 + a5, b3 = a6 + a7;
                h2 c0 = b0 + b1, c1 = b2 + b3;
                acc[k] += ((float)c0.x + (float)c0.y) + ((float)c1.x + (float)c1.y);
            }
        }
    }

    __syncthreads();   // all phase-3 reads of nds complete -> overlay fdbuf

    // ---- write per-node fdiffs (valid-packed, pad-9 stride)
    {
        int h = h0 + tr, w = w0 + tc;
        int cnt = 0;
#pragma unroll
        for (int k = 0; k < 8; ++k) {
            if ((unsigned)(h + OFF_H[k]) < (unsigned)GH &&
                (unsigned)(w + OFF_W[k]) < (unsigned)GW) {
                fdbuf[tid * 9 + cnt] = acc[k] * (1.0f / 64.0f);
                ++cnt;
            }
        }
    }
    __syncthreads();

    // ---- phase 4: edge outputs, edge-major (lane-consecutive NT stores)
#pragma unroll
    for (int r = 0; r < 8; ++r) {
        int u2    = r * 256 + tid;
        int chunk = u2 >> 7;             // tile row 0..15
        int e     = u2 & 127;
        int h     = h0 + chunk;
        int first = degree(h, w0);
        int mid   = degree(h, w0 + 1);
        int last  = degree(h, w0 + TILE - 1);
        int Lr    = first + 14 * mid + last;
        if (e < Lr) {
            int node_in_row, k;
            if (e < first) { node_in_row = 0; k = e; }
            else {
                int m2 = e - first;
                if (mid == 8) { node_in_row = 1 + (m2 >> 3); k = m2 & 7; }
                else          { int q = m2 / 5; node_in_row = 1 + q; k = m2 - 5 * q; }
            }
            int w = w0 + node_in_row;
            int n = h * GW + w;
            int idx = 0, cnt2 = 0;
#pragma unroll
            for (int i = 0; i < 8; ++i) {
                bool ok = (unsigned)(h + OFF_H[i]) < (unsigned)GH &&
                          (unsigned)(w + OFF_W[i]) < (unsigned)GW;
                if (ok) { if (cnt2 == k) idx = i; ++cnt2; }
            }
            int dh = OFF_H[idx], dw = OFF_W[idx];
            float dist = (dh != 0 && dw != 0) ? 1.41421356237f : 1.0f;
            float fd = fdbuf[(chunk * 16 + node_in_row) * 9 + k];
            int o = edge_prefix(h, w0) + e;
            __builtin_nontemporal_store((float)n, ei_out + o);
            __builtin_nontemporal_store((float)(n + dh * GW + dw), ei_out + E + o);
            f2v av; av.x = dist; av.y = fd;
            __builtin_nontemporal_store(av, (f2v*)(attr_out + 2 * (size_t)o));
        }
    }
}

extern "C" void kernel_launch(void* const* d_in, const int* in_sizes, int n_in,
                              void* d_out, int out_size, void* d_ws, size_t ws_size,
                              hipStream_t stream) {
    const float* g = (const float*)d_in[0];    // f32 grid (B,C,H,W)
    int E = in_sizes[1] / 2;                   // 2091012 (ei input not read)

    float* out      = (float*)d_out;
    float* nf_out   = out;                                   // (B*HW, C)  f32
    float* ei_out   = out + (size_t)NB * HW * NC;            // (2, E)     f32
    float* attr_out = ei_out + (size_t)2 * E;                // (E, 2)     f32

    k_fused<<<(GH / TILE) * (GW / TILE), 256, 0, stream>>>(g, nf_out, ei_out, attr_out, E);
}